// Round 4
// baseline (662.267 us; speedup 1.0000x reference)
//
#include <hip/hip_runtime.h>
#include <hip/hip_bf16.h>

#define N_COARSE 12500
#define N_FINE   50000

typedef __bf16 bf16x8 __attribute__((ext_vector_type(8)));
typedef __bf16 bf16x4 __attribute__((ext_vector_type(4)));
typedef float  f32x4  __attribute__((ext_vector_type(4)));

// ---------------------------------------------------------------------------
// Fragment conventions (v_mfma_f32_16x16x32_bf16), HW-verified:
//   a-frag: lane holds A[row = lane&15][k = (lane>>4)*8 + j]
//   b-frag: lane holds B[k = (lane>>4)*8 + j][col = lane&15]
//   d     : lane holds D[row = (lane>>4)*4 + j][col = lane&15]
// ---------------------------------------------------------------------------

__device__ __forceinline__ bf16x8 cvt8(f32x4 x, f32x4 y) {
    bf16x8 r;
    r[0] = (__bf16)x[0]; r[1] = (__bf16)x[1]; r[2] = (__bf16)x[2]; r[3] = (__bf16)x[3];
    r[4] = (__bf16)y[0]; r[5] = (__bf16)y[1]; r[6] = (__bf16)y[2]; r[7] = (__bf16)y[3];
    return r;
}

// Raw barrier with LDS-only fence: __syncthreads() would emit
// s_waitcnt vmcnt(0) and drain our in-flight prefetch loads; we only need
// lgkmcnt(0) (ds_write visibility) before s_barrier. Prefetches stay in
// flight across the barrier (T3/T4 pattern).
__device__ __forceinline__ void lds_barrier() {
    asm volatile("s_waitcnt lgkmcnt(0)" ::: "memory");
    __builtin_amdgcn_s_barrier();
}

// ---- LDS A-tile: [64 rows][256 bf16] = 32 KB, XOR-swizzled ----------------
__device__ __forceinline__ int swz(int row, int byte) { return byte ^ ((row & 7) << 4); }

__device__ __forceinline__ void st_a(__bf16* lds, int row, int cs, bf16x8 v) {
    *(bf16x8*)((char*)lds + swz(row, row * 512 + cs * 16)) = v;
}
__device__ __forceinline__ bf16x8 ld_a(const __bf16* lds, int row, int ka) {
    return *(const bf16x8*)((const char*)lds + swz(row, row * 512 + ka * 2));
}

// issue global loads for a 64x256 f32 tile into regs (no waits here)
template<int NT>
__device__ __forceinline__ void load_f32_tile(const float* __restrict__ A, long row0,
                                              long maxrow, int tid, f32x4* x, f32x4* y) {
    const int r0 = tid >> 5, cs = tid & 31;
    constexpr int RPI = NT / 32;
    #pragma unroll
    for (int i = 0; i < 64 / RPI; ++i) {
        long gr = row0 + r0 + i * RPI; if (gr > maxrow) gr = maxrow;
        const float* p = A + gr * 256 + cs * 8;
        x[i] = *(const f32x4*)p; y[i] = *(const f32x4*)(p + 4);
    }
}
// cvt + ds_write the staged regs (compiler inserts counted vmcnt waits)
template<int NT>
__device__ __forceinline__ void store_tile(__bf16* lds, int tid,
                                           const f32x4* x, const f32x4* y) {
    const int r0 = tid >> 5, cs = tid & 31;
    constexpr int RPI = NT / 32;
    #pragma unroll
    for (int i = 0; i < 64 / RPI; ++i)
        st_a(lds, r0 + i * RPI, cs, cvt8(x[i], y[i]));
}

// 64x64-per-wave MFMA over one 256-wide K segment, A from LDS, B packed global
__device__ __forceinline__ void mfma_tile(const __bf16* lds, const bf16x8* __restrict__ packB,
                                          int N, int c0, int ksb,
                                          f32x4 (&acc)[4][4], int lane) {
    const int g = lane >> 4, r15 = lane & 15;
    #pragma unroll
    for (int ks = 0; ks < 8; ++ks) {
        bf16x8 a[4];
        #pragma unroll
        for (int rt = 0; rt < 4; ++rt)
            a[rt] = ld_a(lds, rt * 16 + r15, ks * 32 + g * 8);
        const size_t kb = (size_t)((ksb + ks) * 4 + g) * N;
        #pragma unroll
        for (int ct = 0; ct < 4; ++ct) {
            bf16x8 b = packB[kb + c0 + ct * 16 + r15];
            #pragma unroll
            for (int rt = 0; rt < 4; ++rt)
                acc[rt][ct] = __builtin_amdgcn_mfma_f32_16x16x32_bf16(a[rt], b, acc[rt][ct], 0, 0, 0);
        }
    }
}

// ---------------------------------------------------------------------------
__global__ __launch_bounds__(256) void k_pack(const float* __restrict__ W,
                                              __bf16* __restrict__ dst, int K, int N) {
    int idx = blockIdx.x * 256 + threadIdx.x;
    if (idx >= K * N) return;
    int k = idx / N, n = idx % N;
    dst[((size_t)(k >> 3) * N + n) * 8 + (k & 7)] = (__bf16)W[(size_t)k * N + n];
}

__global__ __launch_bounds__(256) void k_cvt(const float* __restrict__ src,
                                             __bf16* __restrict__ dst, int n4) {
    int i = blockIdx.x * 256 + threadIdx.x;
    if (i >= n4) return;
    f32x4 v = ((const f32x4*)src)[i];
    bf16x4 o;
    o[0] = (__bf16)v[0]; o[1] = (__bf16)v[1]; o[2] = (__bf16)v[2]; o[3] = (__bf16)v[3];
    ((bf16x4*)dst)[i] = o;
}

// ---------------------------------------------------------------------------
// Coarse: LE = last_equ @ W_last_equ -> LEp in MFMA D-layout (bf16).
// Persistent multi-tile, double-buffered LDS, prefetch-into-regs pipeline.
// ---------------------------------------------------------------------------
__global__ __launch_bounds__(256, 2) void k_coarse_equ(
    const float* __restrict__ last_equ, const bf16x8* __restrict__ packW,
    __bf16* __restrict__ LEp)
{
    __shared__ __attribute__((aligned(16))) __bf16 As[2][64 * 256];
    const int tid = threadIdx.x, lane = tid & 63, wid = tid >> 6;
    const int NTILES = N_COARSE * 16 / 64;                  // 3125
    const int per = (NTILES + gridDim.x - 1) / gridDim.x;   // 5 @ G=625
    const int tbeg = blockIdx.x * per;
    const int tend = min(tbeg + per, NTILES);
    if (tbeg >= tend) return;
    const long maxrow = (long)N_COARSE * 16 - 1;

    f32x4 x[8], y[8];
    load_f32_tile<256>(last_equ, (long)tbeg * 64, maxrow, tid, x, y);
    store_tile<256>(As[0], tid, x, y);
    int cur = 0;
    for (int t = tbeg; t < tend; ++t) {
        lds_barrier();                       // As[cur] ready; prefetches unaffected
        const bool hn = (t + 1 < tend);
        if (hn) load_f32_tile<256>(last_equ, (long)(t + 1) * 64, maxrow, tid, x, y);
        __builtin_amdgcn_sched_barrier(0);   // pin load-issue before MFMA region
        f32x4 acc[4][4] = {};
        mfma_tile(As[cur], packW, 256, wid * 64, 0, acc, lane);
        #pragma unroll
        for (int rt = 0; rt < 4; ++rt) {
            int coarse = t * 4 + rt;
            #pragma unroll
            for (int ct = 0; ct < 4; ++ct) {
                int cg = wid * 4 + ct;
                bf16x4 v;
                v[0] = (__bf16)acc[rt][ct][0]; v[1] = (__bf16)acc[rt][ct][1];
                v[2] = (__bf16)acc[rt][ct][2]; v[3] = (__bf16)acc[rt][ct][3];
                *(bf16x4*)(LEp + ((size_t)(coarse * 16 + cg) * 64 + lane) * 4) = v;
            }
        }
        if (hn) store_tile<256>(As[cur ^ 1], tid, x, y);
        cur ^= 1;
    }
}

// ---------------------------------------------------------------------------
// Fine fused: CE = cur_equ @ W_cur_equ, x gathered LE frag, basis-mean -> equ.
// Same 2-phase pipeline; LE gathers issued alongside next-tile prefetch,
// consumed after MFMA (latency hidden under the matrix phase).
// ---------------------------------------------------------------------------
__global__ __launch_bounds__(256, 2) void k_fine_equ(
    const float* __restrict__ cur_equ, const bf16x8* __restrict__ packW,
    const __bf16* __restrict__ LEp, const int* __restrict__ up,
    __bf16* __restrict__ equ)
{
    __shared__ __attribute__((aligned(16))) __bf16 As[2][64 * 256];
    const int tid = threadIdx.x, lane = tid & 63, wid = tid >> 6;
    const int NTILES = N_FINE / 4;                           // 12500
    const int per = (NTILES + gridDim.x - 1) / gridDim.x;    // 25 @ G=500
    const int tbeg = blockIdx.x * per;
    const int tend = min(tbeg + per, NTILES);
    if (tbeg >= tend) return;
    const long maxrow = (long)N_FINE * 16 - 1;

    f32x4 x[8], y[8];
    load_f32_tile<256>(cur_equ, (long)tbeg * 64, maxrow, tid, x, y);
    store_tile<256>(As[0], tid, x, y);
    int cur = 0;
    for (int t = tbeg; t < tend; ++t) {
        lds_barrier();
        const bool hn = (t + 1 < tend);
        if (hn) load_f32_tile<256>(cur_equ, (long)(t + 1) * 64, maxrow, tid, x, y);
        // LE fragment gathers for tile t (block-uniform indices -> s_load)
        const int n0 = t * 4;
        int cu[4];
        #pragma unroll
        for (int rt = 0; rt < 4; ++rt) cu[rt] = up[n0 + rt];
        bf16x4 le[4][4];
        #pragma unroll
        for (int rt = 0; rt < 4; ++rt)
            #pragma unroll
            for (int ct = 0; ct < 4; ++ct)
                le[rt][ct] = *(const bf16x4*)(LEp +
                    ((size_t)(cu[rt] * 16 + wid * 4 + ct) * 64 + lane) * 4);
        __builtin_amdgcn_sched_barrier(0);
        f32x4 acc[4][4] = {};
        mfma_tile(As[cur], packW, 256, wid * 64, 0, acc, lane);
        #pragma unroll
        for (int rt = 0; rt < 4; ++rt) {
            #pragma unroll
            for (int ct = 0; ct < 4; ++ct) {
                float s = acc[rt][ct][0] * (float)le[rt][ct][0]
                        + acc[rt][ct][1] * (float)le[rt][ct][1]
                        + acc[rt][ct][2] * (float)le[rt][ct][2]
                        + acc[rt][ct][3] * (float)le[rt][ct][3];
                s += __shfl_xor(s, 16, 64);
                s += __shfl_xor(s, 32, 64);
                if (lane < 16)
                    equ[(size_t)(n0 + rt) * 256 + wid * 64 + ct * 16 + lane] =
                        (__bf16)(s * 0.0625f);
            }
        }
        if (hn) store_tile<256>(As[cur ^ 1], tid, x, y);
        cur ^= 1;
    }
}

// ---------------------------------------------------------------------------
// Output: out = [ last_inv[up] | cur_inv | equ ] @ W_mlp  (K=768),
// 512 thr / 8 waves cover all 512 cols in one staging pass; the three
// K-segments are software-pipelined through the two LDS buffers.
// ---------------------------------------------------------------------------
__global__ __launch_bounds__(512) void k_out(
    const __bf16* __restrict__ li_bf, const float* __restrict__ cur_inv,
    const __bf16* __restrict__ equ, const bf16x8* __restrict__ packW,
    const int* __restrict__ up, float* __restrict__ out)
{
    __shared__ __attribute__((aligned(16))) __bf16 As[2][64 * 256];
    const int tid = threadIdx.x, lane = tid & 63, wid = tid >> 6;
    const int row0 = blockIdx.x * 64;
    const int r0 = tid >> 5, cs = tid & 31;
    const int c0 = wid * 64;
    f32x4 acc[4][4] = {};

    // seg0: gathered last_inv rows (bf16) -> buf0
    bf16x8 bz[4];
    #pragma unroll
    for (int i = 0; i < 4; ++i) {
        int gr = row0 + r0 + i * 16; if (gr > N_FINE - 1) gr = N_FINE - 1;
        bz[i] = *(const bf16x8*)(li_bf + (size_t)up[gr] * 256 + cs * 8);
    }
    #pragma unroll
    for (int i = 0; i < 4; ++i) st_a(As[0], r0 + i * 16, cs, bz[i]);

    // stage A: prefetch seg1 (cur_inv f32), MFMA seg0, write buf1
    lds_barrier();
    f32x4 x[4], y[4];
    load_f32_tile<512>(cur_inv, row0, N_FINE - 1, tid, x, y);
    __builtin_amdgcn_sched_barrier(0);
    mfma_tile(As[0], packW, 512, c0, 0, acc, lane);
    store_tile<512>(As[1], tid, x, y);

    // stage B: prefetch seg2 (equ bf16), MFMA seg1, write buf0
    lds_barrier();
    #pragma unroll
    for (int i = 0; i < 4; ++i) {
        int gr = row0 + r0 + i * 16; if (gr > N_FINE - 1) gr = N_FINE - 1;
        bz[i] = *(const bf16x8*)(equ + (size_t)gr * 256 + cs * 8);
    }
    __builtin_amdgcn_sched_barrier(0);
    mfma_tile(As[1], packW, 512, c0, 8, acc, lane);
    #pragma unroll
    for (int i = 0; i < 4; ++i) st_a(As[0], r0 + i * 16, cs, bz[i]);

    // stage C: MFMA seg2, epilogue
    lds_barrier();
    mfma_tile(As[0], packW, 512, c0, 16, acc, lane);

    const int g = lane >> 4, r15 = lane & 15;
    #pragma unroll
    for (int rt = 0; rt < 4; ++rt)
        #pragma unroll
        for (int j = 0; j < 4; ++j) {
            int r = row0 + rt * 16 + g * 4 + j;
            if (r < N_FINE)
                #pragma unroll
                for (int ct = 0; ct < 4; ++ct)
                    out[(size_t)r * 512 + c0 + ct * 16 + r15] = acc[rt][ct][j];
        }
}

extern "C" void kernel_launch(void* const* d_in, const int* in_sizes, int n_in,
                              void* d_out, int out_size, void* d_ws, size_t ws_size,
                              hipStream_t stream) {
    const float* last_inv = (const float*)d_in[0];
    const float* cur_inv  = (const float*)d_in[1];
    const float* last_equ = (const float*)d_in[2];
    const float* cur_equ  = (const float*)d_in[3];
    const int*   up       = (const int*)d_in[4];
    const float* W_le     = (const float*)d_in[5];
    const float* W_ce     = (const float*)d_in[6];
    const float* W_mlp    = (const float*)d_in[7];
    float* out = (float*)d_out;

    // workspace carve-up (~135 MB)
    char* w = (char*)d_ws;
    __bf16* LEp    = (__bf16*)w;  w += (size_t)N_COARSE * 16 * 256 * 2;  // 102.4 MB
    __bf16* equ    = (__bf16*)w;  w += (size_t)N_FINE * 256 * 2;        //  25.6 MB
    __bf16* li_bf  = (__bf16*)w;  w += (size_t)N_COARSE * 256 * 2;      //   6.4 MB
    __bf16* packLE = (__bf16*)w;  w += (size_t)256 * 256 * 2;
    __bf16* packCE = (__bf16*)w;  w += (size_t)256 * 256 * 2;
    __bf16* packM  = (__bf16*)w;  w += (size_t)768 * 512 * 2;

    k_pack<<<256, 256, 0, stream>>>(W_le, packLE, 256, 256);
    k_pack<<<256, 256, 0, stream>>>(W_ce, packCE, 256, 256);
    k_pack<<<1536, 256, 0, stream>>>(W_mlp, packM, 768, 512);
    k_cvt<<<3125, 256, 0, stream>>>(last_inv, li_bf, N_COARSE * 256 / 4);

    k_coarse_equ<<<625, 256, 0, stream>>>(last_equ, (const bf16x8*)packLE, LEp);

    k_fine_equ<<<500, 256, 0, stream>>>(cur_equ, (const bf16x8*)packCE, LEp, up, equ);

    k_out<<<(N_FINE + 63) / 64, 512, 0, stream>>>(
        li_bf, cur_inv, equ, (const bf16x8*)packM, up, out);
}

// Round 5
// 557.271 us; speedup vs baseline: 1.1884x; 1.1884x over previous
//
#include <hip/hip_runtime.h>
#include <hip/hip_bf16.h>

#define N_COARSE 12500
#define N_FINE   50000

typedef __bf16 bf16x8 __attribute__((ext_vector_type(8)));
typedef __bf16 bf16x4 __attribute__((ext_vector_type(4)));
typedef float  f32x4  __attribute__((ext_vector_type(4)));

// ---------------------------------------------------------------------------
// Fragment conventions (v_mfma_f32_16x16x32_bf16), HW-verified:
//   a-frag: lane holds A[row = lane&15][k = (lane>>4)*8 + j]
//   b-frag: lane holds B[k = (lane>>4)*8 + j][col = lane&15]
//   d     : lane holds D[row = (lane>>4)*4 + j][col = lane&15]
// ---------------------------------------------------------------------------

__device__ __forceinline__ bf16x8 cvt8(f32x4 x, f32x4 y) {
    bf16x8 r;
    r[0] = (__bf16)x[0]; r[1] = (__bf16)x[1]; r[2] = (__bf16)x[2]; r[3] = (__bf16)x[3];
    r[4] = (__bf16)y[0]; r[5] = (__bf16)y[1]; r[6] = (__bf16)y[2]; r[7] = (__bf16)y[3];
    return r;
}

// Barrier with LDS-only fence. __syncthreads() emits s_waitcnt vmcnt(0)
// before s_barrier (the m97 barrier-drain) which would drain in-flight
// gather loads; we only need lgkmcnt(0) (ds_write completion). Staging
// loads are already forced complete by their ds_writes' data deps.
__device__ __forceinline__ void lds_barrier() {
    asm volatile("s_waitcnt lgkmcnt(0)" ::: "memory");
    __builtin_amdgcn_s_barrier();
}

// ---- LDS A-tile: [64 rows][256 bf16] = 32 KB, XOR-swizzled ----------------
__device__ __forceinline__ int swz(int row, int byte) { return byte ^ ((row & 7) << 4); }

__device__ __forceinline__ void st_a(__bf16* lds, int row, int cs, bf16x8 v) {
    *(bf16x8*)((char*)lds + swz(row, row * 512 + cs * 16)) = v;
}
__device__ __forceinline__ bf16x8 ld_a(const __bf16* lds, int row, int ka) {
    return *(const bf16x8*)((const char*)lds + swz(row, row * 512 + ka * 2));
}

// stage 64 consecutive f32 rows (256 cols) -> bf16 LDS tile; coalesced loads
template<int NT>
__device__ __forceinline__ void stage_f32(const float* __restrict__ A, long row0,
                                          __bf16* lds, int tid, long maxrow) {
    const int r0 = tid >> 5, cs = tid & 31;
    constexpr int RPI = NT / 32;
    #pragma unroll
    for (int i = 0; i < 64 / RPI; ++i) {
        int row = r0 + i * RPI;
        long gr = row0 + row; if (gr > maxrow) gr = maxrow;
        const float* p = A + gr * 256 + cs * 8;
        f32x4 x = *(const f32x4*)p, y = *(const f32x4*)(p + 4);
        st_a(lds, row, cs, cvt8(x, y));
    }
}

// 64x64-per-wave MFMA over one 256-wide K segment, A from LDS, B packed global
__device__ __forceinline__ void mfma_tile(const __bf16* lds, const bf16x8* __restrict__ packB,
                                          int N, int c0, int ksb,
                                          f32x4 (&acc)[4][4], int lane) {
    const int g = lane >> 4, r15 = lane & 15;
    #pragma unroll
    for (int ks = 0; ks < 8; ++ks) {
        bf16x8 a[4];
        #pragma unroll
        for (int rt = 0; rt < 4; ++rt)
            a[rt] = ld_a(lds, rt * 16 + r15, ks * 32 + g * 8);
        const size_t kb = (size_t)((ksb + ks) * 4 + g) * N;
        #pragma unroll
        for (int ct = 0; ct < 4; ++ct) {
            bf16x8 b = packB[kb + c0 + ct * 16 + r15];
            #pragma unroll
            for (int rt = 0; rt < 4; ++rt)
                acc[rt][ct] = __builtin_amdgcn_mfma_f32_16x16x32_bf16(a[rt], b, acc[rt][ct], 0, 0, 0);
        }
    }
}

// ---------------------------------------------------------------------------
__global__ __launch_bounds__(256) void k_pack(const float* __restrict__ W,
                                              __bf16* __restrict__ dst, int K, int N) {
    int idx = blockIdx.x * 256 + threadIdx.x;
    if (idx >= K * N) return;
    int k = idx / N, n = idx % N;
    dst[((size_t)(k >> 3) * N + n) * 8 + (k & 7)] = (__bf16)W[(size_t)k * N + n];
}

__global__ __launch_bounds__(256) void k_cvt(const float* __restrict__ src,
                                             __bf16* __restrict__ dst, int n4) {
    int i = blockIdx.x * 256 + threadIdx.x;
    if (i >= n4) return;
    f32x4 v = ((const f32x4*)src)[i];
    bf16x4 o;
    o[0] = (__bf16)v[0]; o[1] = (__bf16)v[1]; o[2] = (__bf16)v[2]; o[3] = (__bf16)v[3];
    ((bf16x4*)dst)[i] = o;
}

// ---------------------------------------------------------------------------
// Coarse: LE = last_equ @ W_last_equ -> LEp in MFMA D-layout (bf16).
// One-shot block per 64-row tile (high residency; cross-block TLP hides HBM).
// ---------------------------------------------------------------------------
__global__ __launch_bounds__(256) void k_coarse_equ(
    const float* __restrict__ last_equ, const bf16x8* __restrict__ packW,
    __bf16* __restrict__ LEp)
{
    __shared__ __attribute__((aligned(16))) __bf16 As[64 * 256];
    const int tid = threadIdx.x, lane = tid & 63, wid = tid >> 6;
    const long row0 = (long)blockIdx.x * 64;
    stage_f32<256>(last_equ, row0, As, tid, (long)N_COARSE * 16 - 1);
    lds_barrier();
    f32x4 acc[4][4] = {};
    mfma_tile(As, packW, 256, wid * 64, 0, acc, lane);
    #pragma unroll
    for (int rt = 0; rt < 4; ++rt) {
        int coarse = (int)(row0 >> 4) + rt;
        #pragma unroll
        for (int ct = 0; ct < 4; ++ct) {
            int cg = wid * 4 + ct;
            bf16x4 v;
            v[0] = (__bf16)acc[rt][ct][0]; v[1] = (__bf16)acc[rt][ct][1];
            v[2] = (__bf16)acc[rt][ct][2]; v[3] = (__bf16)acc[rt][ct][3];
            *(bf16x4*)(LEp + ((size_t)(coarse * 16 + cg) * 64 + lane) * 4) = v;
        }
    }
}

// ---------------------------------------------------------------------------
// Fine fused: CE = cur_equ @ W_cur_equ, x gathered LE frag, basis-mean -> equ.
// Issue order matters (FIFO vmcnt): staging loads FIRST, LE gathers LAST,
// then lgkm-only barrier -> gathers stay in flight and drain under the MFMA
// phase instead of at the barrier.
// ---------------------------------------------------------------------------
__global__ __launch_bounds__(256) void k_fine_equ(
    const float* __restrict__ cur_equ, const bf16x8* __restrict__ packW,
    const __bf16* __restrict__ LEp, const int* __restrict__ up,
    __bf16* __restrict__ equ)
{
    __shared__ __attribute__((aligned(16))) __bf16 As[64 * 256];
    const int tid = threadIdx.x, lane = tid & 63, wid = tid >> 6;
    const int n0 = blockIdx.x * 4;
    const long row0 = (long)blockIdx.x * 64;

    int cu[4];
    #pragma unroll
    for (int rt = 0; rt < 4; ++rt) cu[rt] = up[n0 + rt];   // uniform -> s_load

    stage_f32<256>(cur_equ, row0, As, tid, (long)N_FINE * 16 - 1);

    // keep gather issue AFTER the staging loads (compiler must not hoist)
    __builtin_amdgcn_sched_barrier(0);

    bf16x4 le[4][4];
    #pragma unroll
    for (int rt = 0; rt < 4; ++rt)
        #pragma unroll
        for (int ct = 0; ct < 4; ++ct)
            le[rt][ct] = *(const bf16x4*)(LEp +
                ((size_t)(cu[rt] * 16 + wid * 4 + ct) * 64 + lane) * 4);

    lds_barrier();
    f32x4 acc[4][4] = {};
    mfma_tile(As, packW, 256, wid * 64, 0, acc, lane);

    #pragma unroll
    for (int rt = 0; rt < 4; ++rt) {
        int n = n0 + rt;
        #pragma unroll
        for (int ct = 0; ct < 4; ++ct) {
            float s = acc[rt][ct][0] * (float)le[rt][ct][0]
                    + acc[rt][ct][1] * (float)le[rt][ct][1]
                    + acc[rt][ct][2] * (float)le[rt][ct][2]
                    + acc[rt][ct][3] * (float)le[rt][ct][3];
            s += __shfl_xor(s, 16, 64);   // basis reduce over lane-group bit 0
            s += __shfl_xor(s, 32, 64);   // basis reduce over lane-group bit 1
            if (lane < 16)
                equ[(size_t)n * 256 + wid * 64 + ct * 16 + lane] = (__bf16)(s * 0.0625f);
        }
    }
}

// ---------------------------------------------------------------------------
// Output: out = [ last_inv[up] | cur_inv | equ ] @ W_mlp  (K=768)
// 512 thr / 8 waves, one 32-KB buffer, three stage->barrier->MFMA segments;
// lgkm-only barriers avoid the full vmcnt drain.
// ---------------------------------------------------------------------------
__global__ __launch_bounds__(512) void k_out(
    const __bf16* __restrict__ li_bf, const float* __restrict__ cur_inv,
    const __bf16* __restrict__ equ, const bf16x8* __restrict__ packW,
    const int* __restrict__ up, float* __restrict__ out)
{
    __shared__ __attribute__((aligned(16))) __bf16 As[64 * 256];
    const int tid = threadIdx.x, lane = tid & 63, wid = tid >> 6;
    const int row0 = blockIdx.x * 64;
    const int c0 = wid * 64;
    const int r0 = tid >> 5, cs = tid & 31;
    f32x4 acc[4][4] = {};

    // seg0: gathered last_inv rows (bf16)
    #pragma unroll
    for (int i = 0; i < 4; ++i) {
        int row = r0 + i * 16;
        int gr = row0 + row; if (gr > N_FINE - 1) gr = N_FINE - 1;
        st_a(As, row, cs, *(const bf16x8*)(li_bf + (size_t)up[gr] * 256 + cs * 8));
    }
    lds_barrier();
    mfma_tile(As, packW, 512, c0, 0, acc, lane);
    lds_barrier();

    // seg1: cur_inv (f32)
    stage_f32<512>(cur_inv, row0, As, tid, N_FINE - 1);
    lds_barrier();
    mfma_tile(As, packW, 512, c0, 8, acc, lane);
    lds_barrier();

    // seg2: equ (bf16)
    #pragma unroll
    for (int i = 0; i < 4; ++i) {
        int row = r0 + i * 16;
        int gr = row0 + row; if (gr > N_FINE - 1) gr = N_FINE - 1;
        st_a(As, row, cs, *(const bf16x8*)(equ + (size_t)gr * 256 + cs * 8));
    }
    lds_barrier();
    mfma_tile(As, packW, 512, c0, 16, acc, lane);

    const int g = lane >> 4, r15 = lane & 15;
    #pragma unroll
    for (int rt = 0; rt < 4; ++rt)
        #pragma unroll
        for (int j = 0; j < 4; ++j) {
            int r = row0 + rt * 16 + g * 4 + j;
            if (r < N_FINE)
                #pragma unroll
                for (int ct = 0; ct < 4; ++ct)
                    out[(size_t)r * 512 + c0 + ct * 16 + r15] = acc[rt][ct][j];
        }
}

extern "C" void kernel_launch(void* const* d_in, const int* in_sizes, int n_in,
                              void* d_out, int out_size, void* d_ws, size_t ws_size,
                              hipStream_t stream) {
    const float* last_inv = (const float*)d_in[0];
    const float* cur_inv  = (const float*)d_in[1];
    const float* last_equ = (const float*)d_in[2];
    const float* cur_equ  = (const float*)d_in[3];
    const int*   up       = (const int*)d_in[4];
    const float* W_le     = (const float*)d_in[5];
    const float* W_ce     = (const float*)d_in[6];
    const float* W_mlp    = (const float*)d_in[7];
    float* out = (float*)d_out;

    // workspace carve-up (~135 MB)
    char* w = (char*)d_ws;
    __bf16* LEp    = (__bf16*)w;  w += (size_t)N_COARSE * 16 * 256 * 2;  // 102.4 MB
    __bf16* equ    = (__bf16*)w;  w += (size_t)N_FINE * 256 * 2;        //  25.6 MB
    __bf16* li_bf  = (__bf16*)w;  w += (size_t)N_COARSE * 256 * 2;      //   6.4 MB
    __bf16* packLE = (__bf16*)w;  w += (size_t)256 * 256 * 2;
    __bf16* packCE = (__bf16*)w;  w += (size_t)256 * 256 * 2;
    __bf16* packM  = (__bf16*)w;  w += (size_t)768 * 512 * 2;

    k_pack<<<256, 256, 0, stream>>>(W_le, packLE, 256, 256);
    k_pack<<<256, 256, 0, stream>>>(W_ce, packCE, 256, 256);
    k_pack<<<1536, 256, 0, stream>>>(W_mlp, packM, 768, 512);
    k_cvt<<<3125, 256, 0, stream>>>(last_inv, li_bf, N_COARSE * 256 / 4);

    k_coarse_equ<<<N_COARSE * 16 / 64, 256, 0, stream>>>(
        last_equ, (const bf16x8*)packLE, LEp);

    k_fine_equ<<<N_FINE / 4, 256, 0, stream>>>(
        cur_equ, (const bf16x8*)packCE, LEp, up, equ);

    k_out<<<(N_FINE + 63) / 64, 512, 0, stream>>>(
        li_bf, cur_inv, equ, (const bf16x8*)packM, up, out);
}